// Round 8
// baseline (333.431 us; speedup 1.0000x reference)
//
#include <hip/hip_runtime.h>
#include <math.h>

#define N_NODES 500000
#define G_SEG   25000
#define H_DIM   256
#define SPB     4      // segments per kF block

typedef __attribute__((ext_vector_type(4))) float f32x4;
typedef __attribute__((ext_vector_type(8))) short bf16x8;

__device__ __forceinline__ float leaky(float x){ return x > 0.f ? x : 0.01f * x; }

// round-to-nearest-even f32 -> bf16
__device__ __forceinline__ ushort f2bf(float f){
  unsigned u = __float_as_uint(f);
  u += 0x7FFFu + ((u >> 16) & 1u);
  return (ushort)(u >> 16);
}

// K_starts: starts[g] = first row index with seg >= g (sorted seg). starts[G]=N.
__global__ __launch_bounds__(256) void k_starts(
    const int* __restrict__ seg, int* __restrict__ starts)
{
  int i = blockIdx.x * 256 + threadIdx.x;
  if (i >= N_NODES) return;
  int s = seg[i];
  int prev = (i == 0) ? -1 : seg[i - 1];
  for (int g = prev + 1; g <= s; g++) starts[g] = i;
  if (i == N_NODES - 1)
    for (int g = s + 1; g <= G_SEG; g++) starts[g] = N_NODES;
}

// KPack: blocks 0..255 pack w_attend->Bp; blocks 256..767 pack GRU->Bp6.
// Bp:  W[kk][n] -> Bp[((kk>>3)*256 + n)*8 + (kk&7)]
// Bp6: column space n = gate*256+c; gate0 ir+hr, gate1 iz+hz,
//      gate2 inn (K<256), gate3 hn (K>=256);
//      value(kk,n) -> Bp6[((kk>>3)*1024 + n)*8 + (kk&7)]
__global__ __launch_bounds__(256) void kPack(
    const float* __restrict__ w_att, const float* __restrict__ w_ih,
    const float* __restrict__ w_hh, ushort* __restrict__ Bp,
    ushort* __restrict__ Bp6)
{
  int b = blockIdx.x, c = threadIdx.x;
  if (b < 256) {
    int kk = b;
    Bp[(((kk >> 3) << 8) + c) * 8 + (kk & 7)] = f2bf(w_att[kk * H_DIM + c]);
  } else {
    int kk = b - 256;  // 0..511
    #pragma unroll
    for (int gate = 0; gate < 4; gate++) {
      float v;
      if (gate == 0)      v = (kk < 256) ? w_ih[kk * 768 + c]        : w_hh[(kk - 256) * 768 + c];
      else if (gate == 1) v = (kk < 256) ? w_ih[kk * 768 + 256 + c]  : w_hh[(kk - 256) * 768 + 256 + c];
      else if (gate == 2) v = (kk < 256) ? w_ih[kk * 768 + 512 + c]  : 0.f;
      else                v = (kk < 256) ? 0.f                       : w_hh[(kk - 256) * 768 + 512 + c];
      int n = (gate << 8) + c;
      Bp6[(((kk >> 3) << 10) + n) * 8 + (kk & 7)] = f2bf(v);
    }
  }
}

// K1: s = leaky(super_node); sws[g] = dot(s[g], w_align[H:2H])
__global__ __launch_bounds__(256) void k1_prep_super(
    const float* __restrict__ sn, const float* __restrict__ w_align,
    float* __restrict__ s_buf, float* __restrict__ sws)
{
  int g = blockIdx.x, t = threadIdx.x;
  float v = sn[g * H_DIM + t];
  float sv = leaky(v);
  s_buf[g * H_DIM + t] = sv;
  float p = sv * w_align[H_DIM + t];
  #pragma unroll
  for (int d = 1; d < 64; d <<= 1) p += __shfl_xor(p, d);
  __shared__ float red[4];
  int wid = t >> 6, lane = t & 63;
  if (lane == 0) red[wid] = p;
  __syncthreads();
  if (t == 0) sws[g] = red[0] + red[1] + red[2] + red[3];
}

// KF: fused score + segment softmax + weighted aggregation, ONE pass over node.
// (round-6 simple online loop — the explicit 4-row batch of round 7 regressed;
// the compiler already hoists next-row loads across the shfl chain since the
// only carried deps are m/sum/pacc)
__global__ __launch_bounds__(256) void kF_score_softmax_agg(
    const float* __restrict__ node, const int* __restrict__ starts,
    const float* __restrict__ w_align, const float* __restrict__ b_align,
    const float* __restrict__ sws, float* __restrict__ score,
    float* __restrict__ attn_out, float* __restrict__ agg,
    float* __restrict__ bscale)
{
  __shared__ float cpart[4][H_DIM];  // per-wave partial agg (4KB)
  __shared__ float wm[4], wsum[4];
  __shared__ int st_s[SPB + 1];

  const int tid = threadIdx.x;
  const int g0 = blockIdx.x * SPB;
  if (tid <= SPB) st_s[tid] = starts[g0 + tid];
  __syncthreads();

  const int wv = tid >> 6, lane = tid & 63;
  const float4 wvec = ((const float4*)w_align)[lane];
  const float b0 = b_align[0];

  for (int j = 0; j < SPB; j++) {
    const int g = g0 + j;
    const int st = st_s[j], en = st_s[j + 1];
    const float swsg = sws[g];

    float m = -3.4e38f, sum = 0.f;
    f32x4 pacc = {0.f, 0.f, 0.f, 0.f};

    for (int r = st + wv; r < en; r += 4) {
      f32x4 a = ((const f32x4*)node)[(size_t)r * 64 + lane];
      float d = a[0] * wvec.x + a[1] * wvec.y + a[2] * wvec.z + a[3] * wvec.w;
      #pragma unroll
      for (int m2 = 1; m2 < 64; m2 <<= 1) d += __shfl_xor(d, m2);
      float sc = leaky(d + swsg + b0);
      if (lane == 0) score[r] = sc;
      if (sc <= m) {                       // wave-uniform branch
        float p = __expf(sc - m);
        sum += p;
        pacc += p * a;
      } else {
        float scale = __expf(m - sc);      // m=-3.4e38 first time -> 0
        sum = sum * scale + 1.f;
        pacc = pacc * scale + a;
        m = sc;
      }
    }

    if (j > 0) __syncthreads();            // protect cpart/wm reuse
    ((f32x4*)&cpart[wv][0])[lane] = pacc;
    if (lane == 0) { wm[wv] = m; wsum[wv] = sum; }
    __syncthreads();

    float m0 = fmaxf(fmaxf(wm[0], wm[1]), fmaxf(wm[2], wm[3]));
    float f0 = (wm[0] > -1e38f) ? __expf(wm[0] - m0) : 0.f;
    float f1 = (wm[1] > -1e38f) ? __expf(wm[1] - m0) : 0.f;
    float f2 = (wm[2] > -1e38f) ? __expf(wm[2] - m0) : 0.f;
    float f3 = (wm[3] > -1e38f) ? __expf(wm[3] - m0) : 0.f;
    float D = wsum[0] * f0 + wsum[1] * f1 + wsum[2] * f2 + wsum[3] * f3;
    float invD = (D > 0.f) ? 1.f / D : 0.f;

    float v = cpart[0][tid] * f0 + cpart[1][tid] * f1 +
              cpart[2][tid] * f2 + cpart[3][tid] * f3;
    agg[(size_t)g * H_DIM + tid] = v * invD;
    if (tid == 0) bscale[g] = (D > 0.f) ? 1.f : 0.f;

    // attn finalize: score is block-hot
    for (int rr = st + tid; rr < en; rr += 256)
      attn_out[rr] = __expf(score[rr] - m0) * invD;
  }
}

// K56 (fused MFMA): GEMM1 ctx = agg@w_attend + bscale*b_att (32 rows), elu,
// scatter bf16 straight into the gate-GEMM A layout; GEMM2 GRU gates; out.
// Block: 256 thr = 4 waves, 32 segment-rows. No ctx global round-trip.
__global__ __launch_bounds__(256, 2) void k56_fused(
    const float* __restrict__ agg, const float* __restrict__ s_buf,
    const ushort* __restrict__ Bp, const ushort* __restrict__ Bp6,
    const float* __restrict__ b_att, const float* __restrict__ bscale,
    const float* __restrict__ b_ih, const float* __restrict__ b_hh,
    float* __restrict__ out0)
{
  __shared__ __align__(16) ushort Aagg[32 * 256];  // 16KB agg bf16 (swizzled)
  __shared__ __align__(16) ushort A2[32 * 512];    // 32KB [elu(ctx) | s]

  const int tid  = threadIdx.x;
  const int row0 = blockIdx.x * 32;

  // stage agg rows -> Aagg (slots 0..31), s_buf rows -> A2 slots 32..63
  #pragma unroll
  for (int i = 0; i < 4; i++) {
    int v = tid + i * 256;   // 0..1023
    int r = v >> 5;          // 0..31
    int s = v & 31;
    int g = row0 + r;
    f32x4 x0 = {0.f,0.f,0.f,0.f}, x1 = {0.f,0.f,0.f,0.f};
    f32x4 y0 = {0.f,0.f,0.f,0.f}, y1 = {0.f,0.f,0.f,0.f};
    if (g < G_SEG) {
      const f32x4* pa = (const f32x4*)(agg + (size_t)g * H_DIM) + s * 2;
      x0 = pa[0]; x1 = pa[1];
      const f32x4* ps = (const f32x4*)(s_buf + (size_t)g * H_DIM) + s * 2;
      y0 = ps[0]; y1 = ps[1];
    }
    bf16x8 t;
    t[0]=(short)f2bf(x0[0]); t[1]=(short)f2bf(x0[1]);
    t[2]=(short)f2bf(x0[2]); t[3]=(short)f2bf(x0[3]);
    t[4]=(short)f2bf(x1[0]); t[5]=(short)f2bf(x1[1]);
    t[6]=(short)f2bf(x1[2]); t[7]=(short)f2bf(x1[3]);
    *(bf16x8*)&Aagg[r * 256 + ((s ^ (r & 7)) * 8)] = t;
    bf16x8 u;
    u[0]=(short)f2bf(y0[0]); u[1]=(short)f2bf(y0[1]);
    u[2]=(short)f2bf(y0[2]); u[3]=(short)f2bf(y0[3]);
    u[4]=(short)f2bf(y1[0]); u[5]=(short)f2bf(y1[1]);
    u[6]=(short)f2bf(y1[2]); u[7]=(short)f2bf(y1[3]);
    int s2 = s + 32;  // k-slot 32..63
    *(bf16x8*)&A2[r * 512 + ((s2 ^ (r & 7)) * 8)] = u;
  }
  __syncthreads();

  const int wv  = tid >> 6;
  const int l   = tid & 63;
  const int l15 = l & 15, lq = l >> 4, l7 = l & 7;
  const int colbase = wv * 64 + l15;

  // GEMM1: ctx slice (rows mf*16+lq*4+rr, cols colbase+nf*16)
  {
    f32x4 acc1[2][4];
    #pragma unroll
    for (int mf = 0; mf < 2; mf++)
      #pragma unroll
      for (int nf = 0; nf < 4; nf++)
        acc1[mf][nf] = (f32x4){0.f,0.f,0.f,0.f};

    for (int ks = 0; ks < 8; ks++) {
      int c = ks * 4 + lq;
      bf16x8 b[4];
      #pragma unroll
      for (int nf = 0; nf < 4; nf++)
        b[nf] = *(const bf16x8*)&Bp[(((c << 8) + colbase + nf * 16)) * 8];
      bf16x8 a[2];
      #pragma unroll
      for (int mf = 0; mf < 2; mf++)
        a[mf] = *(const bf16x8*)&Aagg[(mf * 16 + l15) * 256 + ((c ^ l7) * 8)];
      #pragma unroll
      for (int mf = 0; mf < 2; mf++)
        #pragma unroll
        for (int nf = 0; nf < 4; nf++)
          acc1[mf][nf] = __builtin_amdgcn_mfma_f32_16x16x32_bf16(
              a[mf], b[nf], acc1[mf][nf], 0, 0, 0);
    }

    // epilogue1: bias*bscale + elu -> bf16 scatter into A2 slots 0..31
    #pragma unroll
    for (int nf = 0; nf < 4; nf++) {
      int k = colbase + nf * 16;       // ctx col = A2 k-index (0..255)
      float bias = b_att[k];
      #pragma unroll
      for (int mf = 0; mf < 2; mf++) {
        #pragma unroll
        for (int rr = 0; rr < 4; rr++) {
          int r = mf * 16 + lq * 4 + rr;
          int grow = row0 + r;
          float bsc = (grow < G_SEG) ? bscale[grow] : 0.f;
          float val = acc1[mf][nf][rr] + bias * bsc;
          val = val > 0.f ? val : (__expf(val) - 1.f);  // elu
          int slot = (k >> 3) ^ (r & 7);
          A2[r * 512 + slot * 8 + (k & 7)] = f2bf(val);
        }
      }
    }
  }
  __syncthreads();

  // GEMM2: gates from A2 (K=512) x Bp6; acc[gate][mf][nf]
  f32x4 acc[4][2][4];
  #pragma unroll
  for (int gt = 0; gt < 4; gt++)
    #pragma unroll
    for (int mf = 0; mf < 2; mf++)
      #pragma unroll
      for (int nf = 0; nf < 4; nf++)
        acc[gt][mf][nf] = (f32x4){0.f,0.f,0.f,0.f};

  for (int ks = 0; ks < 16; ks++) {
    int c = ks * 4 + lq;  // k-chunk 0..63
    bf16x8 a[2];
    #pragma unroll
    for (int mf = 0; mf < 2; mf++)
      a[mf] = *(const bf16x8*)&A2[(mf * 16 + l15) * 512 + ((c ^ l7) * 8)];
    #pragma unroll
    for (int gt = 0; gt < 4; gt++) {
      if (gt == 2 && ks >= 8) continue;  // inn: K<256 only
      if (gt == 3 && ks < 8) continue;   // hn:  K>=256 only
      #pragma unroll
      for (int nf = 0; nf < 4; nf++) {
        int n = (gt << 8) + (wv << 6) + nf * 16 + l15;
        bf16x8 b = *(const bf16x8*)&Bp6[(((c << 10) + n)) * 8];
        acc[gt][0][nf] = __builtin_amdgcn_mfma_f32_16x16x32_bf16(
            a[0], b, acc[gt][0][nf], 0, 0, 0);
        acc[gt][1][nf] = __builtin_amdgcn_mfma_f32_16x16x32_bf16(
            a[1], b, acc[gt][1][nf], 0, 0, 0);
      }
    }
  }

  // epilogue2: GRU combine, relu, store
  #pragma unroll
  for (int nf = 0; nf < 4; nf++) {
    int cc = (wv << 6) + nf * 16 + l15;
    float bir = b_ih[cc] + b_hh[cc];
    float biz = b_ih[256 + cc] + b_hh[256 + cc];
    float bin_ = b_ih[512 + cc];
    float bhn  = b_hh[512 + cc];
    #pragma unroll
    for (int mf = 0; mf < 2; mf++) {
      #pragma unroll
      for (int rr = 0; rr < 4; rr++) {
        int grow = row0 + mf * 16 + lq * 4 + rr;
        if (grow < G_SEG) {
          float v0 = acc[0][mf][nf][rr];
          float v1 = acc[1][mf][nf][rr];
          float v2 = acc[2][mf][nf][rr];
          float v3 = acc[3][mf][nf][rr];
          float r_ = 1.f / (1.f + __expf(-(v0 + bir)));
          float z_ = 1.f / (1.f + __expf(-(v1 + biz)));
          float n_ = tanhf(v2 + bin_ + r_ * (v3 + bhn));
          float sv = s_buf[(size_t)grow * H_DIM + cc];
          float nh = (1.f - z_) * n_ + z_ * sv;
          out0[(size_t)grow * H_DIM + cc] = nh > 0.f ? nh : 0.f;
        }
      }
    }
  }
}

extern "C" void kernel_launch(void* const* d_in, const int* in_sizes, int n_in,
                              void* d_out, int out_size, void* d_ws, size_t ws_size,
                              hipStream_t stream)
{
  (void)in_sizes; (void)n_in; (void)out_size; (void)ws_size;
  const float* node       = (const float*)d_in[0];
  const float* super_node = (const float*)d_in[1];
  const int*   seg        = (const int*)d_in[2];
  const float* w_align    = (const float*)d_in[3];
  const float* b_align    = (const float*)d_in[4];
  const float* w_att      = (const float*)d_in[5];
  const float* b_att      = (const float*)d_in[6];
  const float* w_ih       = (const float*)d_in[7];
  const float* w_hh       = (const float*)d_in[8];
  const float* b_ih       = (const float*)d_in[9];
  const float* b_hh       = (const float*)d_in[10];

  float* out0     = (float*)d_out;                               // G*H
  float* attn_out = (float*)d_out + (size_t)G_SEG * H_DIM;       // N

  float* ws     = (float*)d_ws;
  float* s_buf  = ws;                          //  6,400,000 f32
  float* score  = ws + 6400000;                //    500,000 (kF scratch)
  float* sws    = ws + 6900000;                //     25,000
  float* agg    = ws + 6925000;                //  6,400,000
  ushort* Bp    = (ushort*)(ws + 13325000);    //  65,536 ushort (128KB)
  ushort* Bp6   = (ushort*)(ws + 13360000);    // 524,288 ushort (1MB)
  float* bscale = ws + 13625000;               //     25,000
  int*   starts = (int*)(ws + 13650000);       //     25,001 int (end ~54.7MB)

  k_starts<<<(N_NODES + 255) / 256, 256, 0, stream>>>(seg, starts);
  kPack<<<768, 256, 0, stream>>>(w_att, w_ih, w_hh, Bp, Bp6);
  k1_prep_super<<<G_SEG, 256, 0, stream>>>(super_node, w_align, s_buf, sws);
  kF_score_softmax_agg<<<G_SEG / SPB, 256, 0, stream>>>(
      node, starts, w_align, b_align, sws, score, attn_out, agg, bscale);
  k56_fused<<<(G_SEG + 31) / 32, 256, 0, stream>>>(
      agg, s_buf, Bp, Bp6, b_att, bscale, b_ih, b_hh, out0);
}

// Round 9
// 277.631 us; speedup vs baseline: 1.2010x; 1.2010x over previous
//
#include <hip/hip_runtime.h>
#include <math.h>

#define N_NODES 500000
#define G_SEG   25000
#define H_DIM   256
#define SPB     4      // segments per kF block

typedef __attribute__((ext_vector_type(4))) float f32x4;
typedef __attribute__((ext_vector_type(8))) short bf16x8;

__device__ __forceinline__ float leaky(float x){ return x > 0.f ? x : 0.01f * x; }

// round-to-nearest-even f32 -> bf16
__device__ __forceinline__ ushort f2bf(float f){
  unsigned u = __float_as_uint(f);
  u += 0x7FFFu + ((u >> 16) & 1u);
  return (ushort)(u >> 16);
}

// K_starts: starts[g] = first row index with seg >= g (sorted seg). starts[G]=N.
__global__ __launch_bounds__(256) void k_starts(
    const int* __restrict__ seg, int* __restrict__ starts)
{
  int i = blockIdx.x * 256 + threadIdx.x;
  if (i >= N_NODES) return;
  int s = seg[i];
  int prev = (i == 0) ? -1 : seg[i - 1];
  for (int g = prev + 1; g <= s; g++) starts[g] = i;
  if (i == N_NODES - 1)
    for (int g = s + 1; g <= G_SEG; g++) starts[g] = N_NODES;
}

// KPack: blocks 0..255 pack w_attend->Bp; blocks 256..767 pack GRU->Bp6.
// Bp:  W[kk][n] -> Bp[((kk>>3)*256 + n)*8 + (kk&7)]
// Bp6: n = gate*256+c; gate0 ir+hr, gate1 iz+hz, gate2 inn (K<256),
//      gate3 hn (K>=256); value(kk,n) -> Bp6[((kk>>3)*1024 + n)*8 + (kk&7)]
__global__ __launch_bounds__(256) void kPack(
    const float* __restrict__ w_att, const float* __restrict__ w_ih,
    const float* __restrict__ w_hh, ushort* __restrict__ Bp,
    ushort* __restrict__ Bp6)
{
  int b = blockIdx.x, c = threadIdx.x;
  if (b < 256) {
    int kk = b;
    Bp[(((kk >> 3) << 8) + c) * 8 + (kk & 7)] = f2bf(w_att[kk * H_DIM + c]);
  } else {
    int kk = b - 256;  // 0..511
    #pragma unroll
    for (int gate = 0; gate < 4; gate++) {
      float v;
      if (gate == 0)      v = (kk < 256) ? w_ih[kk * 768 + c]        : w_hh[(kk - 256) * 768 + c];
      else if (gate == 1) v = (kk < 256) ? w_ih[kk * 768 + 256 + c]  : w_hh[(kk - 256) * 768 + 256 + c];
      else if (gate == 2) v = (kk < 256) ? w_ih[kk * 768 + 512 + c]  : 0.f;
      else                v = (kk < 256) ? 0.f                       : w_hh[(kk - 256) * 768 + 512 + c];
      int n = (gate << 8) + c;
      Bp6[(((kk >> 3) << 10) + n) * 8 + (kk & 7)] = f2bf(v);
    }
  }
}

// K1: s = leaky(super_node); sws[g] = dot(s[g], w_align[H:2H])
__global__ __launch_bounds__(256) void k1_prep_super(
    const float* __restrict__ sn, const float* __restrict__ w_align,
    float* __restrict__ s_buf, float* __restrict__ sws)
{
  int g = blockIdx.x, t = threadIdx.x;
  float v = sn[g * H_DIM + t];
  float sv = leaky(v);
  s_buf[g * H_DIM + t] = sv;
  float p = sv * w_align[H_DIM + t];
  #pragma unroll
  for (int d = 1; d < 64; d <<= 1) p += __shfl_xor(p, d);
  __shared__ float red[4];
  int wid = t >> 6, lane = t & 63;
  if (lane == 0) red[wid] = p;
  __syncthreads();
  if (t == 0) sws[g] = red[0] + red[1] + red[2] + red[3];
}

// KF: fused score + segment softmax + weighted aggregation, ONE pass over node.
// 4-row ILP batch (4 interleaved shfl-reduce chains amortize the 6-hop
// latency; measured −5 µs in R7-vs-R8). Raw scores stored into attn_out,
// finalized in-place after the segment combine. No atomics, no extra scratch.
__global__ __launch_bounds__(256) void kF_score_softmax_agg(
    const float* __restrict__ node, const int* __restrict__ starts,
    const float* __restrict__ w_align, const float* __restrict__ b_align,
    const float* __restrict__ sws,
    float* __restrict__ attn_out, float* __restrict__ agg,
    float* __restrict__ bscale)
{
  __shared__ float cpart[4][H_DIM];  // per-wave partial agg (4KB)
  __shared__ float wm[4], wsum[4];
  __shared__ int st_s[SPB + 1];

  const int tid = threadIdx.x;
  const int g0 = blockIdx.x * SPB;
  if (tid <= SPB) st_s[tid] = starts[g0 + tid];
  __syncthreads();

  const int wv = tid >> 6, lane = tid & 63;
  const float4 wvec = ((const float4*)w_align)[lane];
  const float b0 = b_align[0];

  for (int j = 0; j < SPB; j++) {
    const int g = g0 + j;
    const int st = st_s[j], en = st_s[j + 1];
    const float swsg = sws[g];

    float m = -3.4e38f, sum = 0.f;
    f32x4 pacc = {0.f, 0.f, 0.f, 0.f};

    int r = st + wv;
    // 4-row batch: rows r, r+4, r+8, r+12 (this wave's stride is 4)
    for (; r + 12 < en; r += 16) {
      f32x4 a0 = ((const f32x4*)node)[(size_t)(r     ) * 64 + lane];
      f32x4 a1 = ((const f32x4*)node)[(size_t)(r +  4) * 64 + lane];
      f32x4 a2 = ((const f32x4*)node)[(size_t)(r +  8) * 64 + lane];
      f32x4 a3 = ((const f32x4*)node)[(size_t)(r + 12) * 64 + lane];
      float d0 = a0[0]*wvec.x + a0[1]*wvec.y + a0[2]*wvec.z + a0[3]*wvec.w;
      float d1 = a1[0]*wvec.x + a1[1]*wvec.y + a1[2]*wvec.z + a1[3]*wvec.w;
      float d2 = a2[0]*wvec.x + a2[1]*wvec.y + a2[2]*wvec.z + a2[3]*wvec.w;
      float d3 = a3[0]*wvec.x + a3[1]*wvec.y + a3[2]*wvec.z + a3[3]*wvec.w;
      #pragma unroll
      for (int s2 = 1; s2 < 64; s2 <<= 1) {
        d0 += __shfl_xor(d0, s2);
        d1 += __shfl_xor(d1, s2);
        d2 += __shfl_xor(d2, s2);
        d3 += __shfl_xor(d3, s2);
      }
      float sc0 = leaky(d0 + swsg + b0);
      float sc1 = leaky(d1 + swsg + b0);
      float sc2 = leaky(d2 + swsg + b0);
      float sc3 = leaky(d3 + swsg + b0);
      if (lane == 0) {
        attn_out[r] = sc0; attn_out[r + 4] = sc1;
        attn_out[r + 8] = sc2; attn_out[r + 12] = sc3;
      }
      float bm = fmaxf(fmaxf(sc0, sc1), fmaxf(sc2, sc3));
      if (bm > m) {                      // wave-uniform
        float scale = __expf(m - bm);    // first time: exp(-inf) = 0
        sum *= scale; pacc *= scale; m = bm;
      }
      float p0 = __expf(sc0 - m), p1 = __expf(sc1 - m);
      float p2 = __expf(sc2 - m), p3 = __expf(sc3 - m);
      sum += (p0 + p1) + (p2 + p3);
      pacc += p0 * a0 + p1 * a1;
      pacc += p2 * a2 + p3 * a3;
    }
    // tail rows
    for (; r < en; r += 4) {
      f32x4 a = ((const f32x4*)node)[(size_t)r * 64 + lane];
      float d = a[0]*wvec.x + a[1]*wvec.y + a[2]*wvec.z + a[3]*wvec.w;
      #pragma unroll
      for (int s2 = 1; s2 < 64; s2 <<= 1) d += __shfl_xor(d, s2);
      float sc = leaky(d + swsg + b0);
      if (lane == 0) attn_out[r] = sc;
      if (sc <= m) {
        float p = __expf(sc - m);
        sum += p;
        pacc += p * a;
      } else {
        float scale = __expf(m - sc);
        sum = sum * scale + 1.f;
        pacc = pacc * scale + a;
        m = sc;
      }
    }

    if (j > 0) __syncthreads();            // protect cpart/wm reuse
    ((f32x4*)&cpart[wv][0])[lane] = pacc;
    if (lane == 0) { wm[wv] = m; wsum[wv] = sum; }
    __syncthreads();

    float m0 = fmaxf(fmaxf(wm[0], wm[1]), fmaxf(wm[2], wm[3]));
    float f0 = (wm[0] > -1e38f) ? __expf(wm[0] - m0) : 0.f;
    float f1 = (wm[1] > -1e38f) ? __expf(wm[1] - m0) : 0.f;
    float f2 = (wm[2] > -1e38f) ? __expf(wm[2] - m0) : 0.f;
    float f3 = (wm[3] > -1e38f) ? __expf(wm[3] - m0) : 0.f;
    float D = wsum[0] * f0 + wsum[1] * f1 + wsum[2] * f2 + wsum[3] * f3;
    float invD = (D > 0.f) ? 1.f / D : 0.f;

    float v = cpart[0][tid] * f0 + cpart[1][tid] * f1 +
              cpart[2][tid] * f2 + cpart[3][tid] * f3;
    agg[(size_t)g * H_DIM + tid] = v * invD;
    if (tid == 0) bscale[g] = (D > 0.f) ? 1.f : 0.f;

    // attn finalize in-place (scores are block-hot; barrier above ordered them)
    for (int rr = st + tid; rr < en; rr += 256)
      attn_out[rr] = __expf(attn_out[rr] - m0) * invD;
  }
}

// K5b (MFMA): ctx = agg @ w_attend + bscale*b_attend  (G x 256 @ 256 x 256).
__global__ __launch_bounds__(256, 2) void k5b_ctx(
    const float* __restrict__ agg, const ushort* __restrict__ Bp,
    const float* __restrict__ b_att, const float* __restrict__ bscale,
    float* __restrict__ ctx)
{
  __shared__ __align__(16) ushort A_lds[128 * 256];  // 64KB

  const int tid  = threadIdx.x;
  const int row0 = blockIdx.x * 128;

  #pragma unroll
  for (int i = 0; i < 16; i++) {
    int v = tid + i * 256;
    int r = v >> 5;
    int s = v & 31;
    int grow = row0 + r;
    f32x4 x0 = {0.f, 0.f, 0.f, 0.f}, x1 = {0.f, 0.f, 0.f, 0.f};
    if (grow < G_SEG) {
      const f32x4* p = (const f32x4*)(agg + (size_t)grow * H_DIM) + s * 2;
      x0 = p[0]; x1 = p[1];
    }
    bf16x8 t;
    t[0] = (short)f2bf(x0[0]); t[1] = (short)f2bf(x0[1]);
    t[2] = (short)f2bf(x0[2]); t[3] = (short)f2bf(x0[3]);
    t[4] = (short)f2bf(x1[0]); t[5] = (short)f2bf(x1[1]);
    t[6] = (short)f2bf(x1[2]); t[7] = (short)f2bf(x1[3]);
    *(bf16x8*)&A_lds[r * 256 + ((s ^ (r & 7)) * 8)] = t;
  }
  __syncthreads();

  const int wv  = tid >> 6;
  const int l   = tid & 63;
  const int l15 = l & 15, lq = l >> 4, l7 = l & 7;
  const int colbase = wv * 64 + l15;

  f32x4 acc[8][4];
  #pragma unroll
  for (int mf = 0; mf < 8; mf++)
    #pragma unroll
    for (int nf = 0; nf < 4; nf++)
      acc[mf][nf] = (f32x4){0.f, 0.f, 0.f, 0.f};

  for (int ks = 0; ks < 8; ks++) {
    int c = ks * 4 + lq;
    bf16x8 b[4];
    #pragma unroll
    for (int nf = 0; nf < 4; nf++)
      b[nf] = *(const bf16x8*)&Bp[(((c << 8) + colbase + nf * 16)) * 8];
    bf16x8 a[8];
    #pragma unroll
    for (int mf = 0; mf < 8; mf++)
      a[mf] = *(const bf16x8*)&A_lds[(mf * 16 + l15) * 256 + ((c ^ l7) * 8)];
    #pragma unroll
    for (int mf = 0; mf < 8; mf++)
      #pragma unroll
      for (int nf = 0; nf < 4; nf++)
        acc[mf][nf] = __builtin_amdgcn_mfma_f32_16x16x32_bf16(
            a[mf], b[nf], acc[mf][nf], 0, 0, 0);
  }

  float bias[4];
  #pragma unroll
  for (int nf = 0; nf < 4; nf++) bias[nf] = b_att[colbase + nf * 16];

  #pragma unroll
  for (int mf = 0; mf < 8; mf++) {
    #pragma unroll
    for (int r = 0; r < 4; r++) {
      int grow = row0 + mf * 16 + lq * 4 + r;
      if (grow < G_SEG) {
        float bsc = bscale[grow];
        #pragma unroll
        for (int nf = 0; nf < 4; nf++)
          ctx[(size_t)grow * H_DIM + colbase + nf * 16] =
              acc[mf][nf][r] + bias[nf] * bsc;
      }
    }
  }
}

// K6 (MFMA) v2: wave owns a 64-col slice for ALL 4 gates (acc[4][2][4],
// statically indexed) -> no gate_s LDS, single barrier, balanced waves.
__global__ __launch_bounds__(256, 2) void k6_mfma(
    const float* __restrict__ ctxbuf, const float* __restrict__ s_buf,
    const ushort* __restrict__ Bp6,
    const float* __restrict__ b_ih, const float* __restrict__ b_hh,
    float* __restrict__ out0)
{
  __shared__ __align__(16) ushort A_lds[32 * 512];   // 32KB

  const int tid  = threadIdx.x;
  const int row0 = blockIdx.x * 32;

  #pragma unroll
  for (int i = 0; i < 8; i++) {
    int v = tid + i * 256;
    int r = v >> 6;
    int s = v & 63;
    int g = row0 + r;
    f32x4 x0 = {0.f, 0.f, 0.f, 0.f}, x1 = {0.f, 0.f, 0.f, 0.f};
    if (g < G_SEG) {
      const f32x4* p = (s < 32)
          ? (const f32x4*)(ctxbuf + (size_t)g * H_DIM) + s * 2
          : (const f32x4*)(s_buf + (size_t)g * H_DIM) + (s - 32) * 2;
      x0 = p[0]; x1 = p[1];
      if (s < 32) {
        #pragma unroll
        for (int e = 0; e < 4; e++) {
          x0[e] = x0[e] > 0.f ? x0[e] : (__expf(x0[e]) - 1.f);
          x1[e] = x1[e] > 0.f ? x1[e] : (__expf(x1[e]) - 1.f);
        }
      }
    }
    bf16x8 t;
    t[0] = (short)f2bf(x0[0]); t[1] = (short)f2bf(x0[1]);
    t[2] = (short)f2bf(x0[2]); t[3] = (short)f2bf(x0[3]);
    t[4] = (short)f2bf(x1[0]); t[5] = (short)f2bf(x1[1]);
    t[6] = (short)f2bf(x1[2]); t[7] = (short)f2bf(x1[3]);
    *(bf16x8*)&A_lds[r * 512 + ((s ^ (r & 7)) * 8)] = t;
  }
  __syncthreads();

  const int wv  = tid >> 6;
  const int l   = tid & 63;
  const int l15 = l & 15, lq = l >> 4, l7 = l & 7;

  f32x4 acc[4][2][4];  // [gate][mf][nf]
  #pragma unroll
  for (int gt = 0; gt < 4; gt++)
    #pragma unroll
    for (int mf = 0; mf < 2; mf++)
      #pragma unroll
      for (int nf = 0; nf < 4; nf++)
        acc[gt][mf][nf] = (f32x4){0.f, 0.f, 0.f, 0.f};

  for (int ks = 0; ks < 16; ks++) {
    int c = ks * 4 + lq;  // k-chunk 0..63
    bf16x8 a[2];
    #pragma unroll
    for (int mf = 0; mf < 2; mf++)
      a[mf] = *(const bf16x8*)&A_lds[(mf * 16 + l15) * 512 + ((c ^ l7) * 8)];
    #pragma unroll
    for (int gt = 0; gt < 4; gt++) {
      if (gt == 2 && ks >= 8) continue;  // inn: K<256 only
      if (gt == 3 && ks < 8) continue;   // hn:  K>=256 only
      #pragma unroll
      for (int nf = 0; nf < 4; nf++) {
        int n = (gt << 8) + (wv << 6) + nf * 16 + l15;
        bf16x8 b = *(const bf16x8*)&Bp6[(((c << 10) + n)) * 8];
        acc[gt][0][nf] = __builtin_amdgcn_mfma_f32_16x16x32_bf16(
            a[0], b, acc[gt][0][nf], 0, 0, 0);
        acc[gt][1][nf] = __builtin_amdgcn_mfma_f32_16x16x32_bf16(
            a[1], b, acc[gt][1][nf], 0, 0, 0);
      }
    }
  }

  // epilogue fully in-register
  #pragma unroll
  for (int nf = 0; nf < 4; nf++) {
    int cc = (wv << 6) + nf * 16 + l15;
    float bir = b_ih[cc] + b_hh[cc];
    float biz = b_ih[256 + cc] + b_hh[256 + cc];
    float bin_ = b_ih[512 + cc];
    float bhn  = b_hh[512 + cc];
    #pragma unroll
    for (int mf = 0; mf < 2; mf++) {
      #pragma unroll
      for (int rr = 0; rr < 4; rr++) {
        int grow = row0 + mf * 16 + lq * 4 + rr;
        if (grow < G_SEG) {
          float v0 = acc[0][mf][nf][rr];
          float v1 = acc[1][mf][nf][rr];
          float v2 = acc[2][mf][nf][rr];
          float v3 = acc[3][mf][nf][rr];
          float r_ = 1.f / (1.f + __expf(-(v0 + bir)));
          float z_ = 1.f / (1.f + __expf(-(v1 + biz)));
          float n_ = tanhf(v2 + bin_ + r_ * (v3 + bhn));
          float sv = s_buf[(size_t)grow * H_DIM + cc];
          float nh = (1.f - z_) * n_ + z_ * sv;
          out0[(size_t)grow * H_DIM + cc] = nh > 0.f ? nh : 0.f;
        }
      }
    }
  }
}

extern "C" void kernel_launch(void* const* d_in, const int* in_sizes, int n_in,
                              void* d_out, int out_size, void* d_ws, size_t ws_size,
                              hipStream_t stream)
{
  (void)in_sizes; (void)n_in; (void)out_size; (void)ws_size;
  const float* node       = (const float*)d_in[0];
  const float* super_node = (const float*)d_in[1];
  const int*   seg        = (const int*)d_in[2];
  const float* w_align    = (const float*)d_in[3];
  const float* b_align    = (const float*)d_in[4];
  const float* w_att      = (const float*)d_in[5];
  const float* b_att      = (const float*)d_in[6];
  const float* w_ih       = (const float*)d_in[7];
  const float* w_hh       = (const float*)d_in[8];
  const float* b_ih       = (const float*)d_in[9];
  const float* b_hh       = (const float*)d_in[10];

  float* out0     = (float*)d_out;                               // G*H
  float* attn_out = (float*)d_out + (size_t)G_SEG * H_DIM;       // N

  float* ws     = (float*)d_ws;
  float* s_buf  = ws;                          //  6,400,000 f32
  float* sws    = ws + 6400000;                //     25,000
  float* agg    = ws + 6425000;                //  6,400,000
  ushort* Bp    = (ushort*)(ws + 12825000);    //  65,536 ushort (128KB)
  ushort* Bp6   = (ushort*)(ws + 12860000);    // 524,288 ushort (1MB)
  float* bscale = ws + 13125000;               //     25,000
  int*   starts = (int*)(ws + 13150000);       //     25,001 int
  float* ctx    = ws + 13200000;               //  6,400,000 (end 19.6M f32 = 78.4MB)

  k_starts<<<(N_NODES + 255) / 256, 256, 0, stream>>>(seg, starts);
  kPack<<<768, 256, 0, stream>>>(w_att, w_ih, w_hh, Bp, Bp6);
  k1_prep_super<<<G_SEG, 256, 0, stream>>>(super_node, w_align, s_buf, sws);
  kF_score_softmax_agg<<<G_SEG / SPB, 256, 0, stream>>>(
      node, starts, w_align, b_align, sws, attn_out, agg, bscale);
  k5b_ctx<<<(G_SEG + 127) / 128, 256, 0, stream>>>(agg, Bp, b_att, bscale, ctx);
  k6_mfma<<<(G_SEG + 31) / 32, 256, 0, stream>>>(ctx, s_buf, Bp6, b_ih, b_hh, out0);
}

// Round 10
// 270.381 us; speedup vs baseline: 1.2332x; 1.0268x over previous
//
#include <hip/hip_runtime.h>
#include <math.h>

#define N_NODES 500000
#define G_SEG   25000
#define H_DIM   256
#define SPB     4      // segments per kF block (one per wave)

typedef __attribute__((ext_vector_type(4))) float f32x4;
typedef __attribute__((ext_vector_type(8))) short bf16x8;

__device__ __forceinline__ float leaky(float x){ return x > 0.f ? x : 0.01f * x; }

// round-to-nearest-even f32 -> bf16
__device__ __forceinline__ ushort f2bf(float f){
  unsigned u = __float_as_uint(f);
  u += 0x7FFFu + ((u >> 16) & 1u);
  return (ushort)(u >> 16);
}

// K_starts: starts[g] = first row index with seg >= g (sorted seg). starts[G]=N.
__global__ __launch_bounds__(256) void k_starts(
    const int* __restrict__ seg, int* __restrict__ starts)
{
  int i = blockIdx.x * 256 + threadIdx.x;
  if (i >= N_NODES) return;
  int s = seg[i];
  int prev = (i == 0) ? -1 : seg[i - 1];
  for (int g = prev + 1; g <= s; g++) starts[g] = i;
  if (i == N_NODES - 1)
    for (int g = s + 1; g <= G_SEG; g++) starts[g] = N_NODES;
}

// KPack: blocks 0..255 pack w_attend->Bp; blocks 256..767 pack GRU->Bp6.
// Bp:  W[kk][n] -> Bp[((kk>>3)*256 + n)*8 + (kk&7)]
// Bp6: n = gate*256+c; gate0 ir+hr, gate1 iz+hz, gate2 inn (K<256),
//      gate3 hn (K>=256); value(kk,n) -> Bp6[((kk>>3)*1024 + n)*8 + (kk&7)]
__global__ __launch_bounds__(256) void kPack(
    const float* __restrict__ w_att, const float* __restrict__ w_ih,
    const float* __restrict__ w_hh, ushort* __restrict__ Bp,
    ushort* __restrict__ Bp6)
{
  int b = blockIdx.x, c = threadIdx.x;
  if (b < 256) {
    int kk = b;
    Bp[(((kk >> 3) << 8) + c) * 8 + (kk & 7)] = f2bf(w_att[kk * H_DIM + c]);
  } else {
    int kk = b - 256;  // 0..511
    #pragma unroll
    for (int gate = 0; gate < 4; gate++) {
      float v;
      if (gate == 0)      v = (kk < 256) ? w_ih[kk * 768 + c]        : w_hh[(kk - 256) * 768 + c];
      else if (gate == 1) v = (kk < 256) ? w_ih[kk * 768 + 256 + c]  : w_hh[(kk - 256) * 768 + 256 + c];
      else if (gate == 2) v = (kk < 256) ? w_ih[kk * 768 + 512 + c]  : 0.f;
      else                v = (kk < 256) ? 0.f                       : w_hh[(kk - 256) * 768 + 512 + c];
      int n = (gate << 8) + c;
      Bp6[(((kk >> 3) << 10) + n) * 8 + (kk & 7)] = f2bf(v);
    }
  }
}

// K1: s = leaky(super_node); sws[g] = dot(s[g], w_align[H:2H])
__global__ __launch_bounds__(256) void k1_prep_super(
    const float* __restrict__ sn, const float* __restrict__ w_align,
    float* __restrict__ s_buf, float* __restrict__ sws)
{
  int g = blockIdx.x, t = threadIdx.x;
  float v = sn[g * H_DIM + t];
  float sv = leaky(v);
  s_buf[g * H_DIM + t] = sv;
  float p = sv * w_align[H_DIM + t];
  #pragma unroll
  for (int d = 1; d < 64; d <<= 1) p += __shfl_xor(p, d);
  __shared__ float red[4];
  int wid = t >> 6, lane = t & 63;
  if (lane == 0) red[wid] = p;
  __syncthreads();
  if (t == 0) sws[g] = red[0] + red[1] + red[2] + red[3];
}

// KF v3: wave-per-segment. Each wave independently owns one segment:
// zero barriers, zero LDS combine, contiguous 4-row ILP batches, online
// softmax state (m, sum, pacc) entirely in registers. Raw scores parked in
// attn_out, finalized in-wave (L1-hot re-read). Direct agg store, no atomics.
__global__ __launch_bounds__(256) void kF_score_softmax_agg(
    const float* __restrict__ node, const int* __restrict__ starts,
    const float* __restrict__ w_align, const float* __restrict__ b_align,
    const float* __restrict__ sws,
    float* __restrict__ attn_out, float* __restrict__ agg,
    float* __restrict__ bscale)
{
  __shared__ int st_s[SPB + 1];
  const int tid = threadIdx.x;
  const int g0 = blockIdx.x * SPB;
  if (tid <= SPB) st_s[tid] = starts[g0 + tid];
  __syncthreads();

  const int wv = tid >> 6, lane = tid & 63;
  const float4 wvec = ((const float4*)w_align)[lane];
  const float b0 = b_align[0];

  const int g  = g0 + wv;
  const int st = st_s[wv], en = st_s[wv + 1];
  const float swsg = sws[g];

  float m = -3.4e38f, sum = 0.f;
  f32x4 pacc = {0.f, 0.f, 0.f, 0.f};

  int r = st;
  // 4 contiguous rows per iteration: 4 loads in flight, 4 interleaved
  // shfl-reduce chains
  for (; r + 3 < en; r += 4) {
    f32x4 a0 = ((const f32x4*)node)[(size_t)(r    ) * 64 + lane];
    f32x4 a1 = ((const f32x4*)node)[(size_t)(r + 1) * 64 + lane];
    f32x4 a2 = ((const f32x4*)node)[(size_t)(r + 2) * 64 + lane];
    f32x4 a3 = ((const f32x4*)node)[(size_t)(r + 3) * 64 + lane];
    float d0 = a0[0]*wvec.x + a0[1]*wvec.y + a0[2]*wvec.z + a0[3]*wvec.w;
    float d1 = a1[0]*wvec.x + a1[1]*wvec.y + a1[2]*wvec.z + a1[3]*wvec.w;
    float d2 = a2[0]*wvec.x + a2[1]*wvec.y + a2[2]*wvec.z + a2[3]*wvec.w;
    float d3 = a3[0]*wvec.x + a3[1]*wvec.y + a3[2]*wvec.z + a3[3]*wvec.w;
    #pragma unroll
    for (int s2 = 1; s2 < 64; s2 <<= 1) {
      d0 += __shfl_xor(d0, s2);
      d1 += __shfl_xor(d1, s2);
      d2 += __shfl_xor(d2, s2);
      d3 += __shfl_xor(d3, s2);
    }
    float sc0 = leaky(d0 + swsg + b0);
    float sc1 = leaky(d1 + swsg + b0);
    float sc2 = leaky(d2 + swsg + b0);
    float sc3 = leaky(d3 + swsg + b0);
    if (lane < 4) {
      float scs = (lane == 0) ? sc0 : (lane == 1) ? sc1 : (lane == 2) ? sc2 : sc3;
      attn_out[r + lane] = scs;   // raw score parked
    }
    float bm = fmaxf(fmaxf(sc0, sc1), fmaxf(sc2, sc3));
    if (bm > m) {                      // wave-uniform
      float scale = __expf(m - bm);    // first time: exp(-inf) = 0
      sum *= scale; pacc *= scale; m = bm;
    }
    float p0 = __expf(sc0 - m), p1 = __expf(sc1 - m);
    float p2 = __expf(sc2 - m), p3 = __expf(sc3 - m);
    sum += (p0 + p1) + (p2 + p3);
    pacc += p0 * a0 + p1 * a1;
    pacc += p2 * a2 + p3 * a3;
  }
  // tail rows
  for (; r < en; r++) {
    f32x4 a = ((const f32x4*)node)[(size_t)r * 64 + lane];
    float d = a[0]*wvec.x + a[1]*wvec.y + a[2]*wvec.z + a[3]*wvec.w;
    #pragma unroll
    for (int s2 = 1; s2 < 64; s2 <<= 1) d += __shfl_xor(d, s2);
    float sc = leaky(d + swsg + b0);
    if (lane == 0) attn_out[r] = sc;
    if (sc <= m) {
      float p = __expf(sc - m);
      sum += p;
      pacc += p * a;
    } else {
      float scale = __expf(m - sc);
      sum = sum * scale + 1.f;
      pacc = pacc * scale + a;
      m = sc;
    }
  }

  // wave-local finalize
  float invD = (sum > 0.f) ? 1.f / sum : 0.f;
  ((f32x4*)(agg + (size_t)g * H_DIM))[lane] = pacc * invD;
  if (lane == 0) bscale[g] = (sum > 0.f) ? 1.f : 0.f;
  for (int rr = st + lane; rr < en; rr += 64)
    attn_out[rr] = __expf(attn_out[rr] - m) * invD;
}

// K5b (MFMA): ctx = agg @ w_attend + bscale*b_attend  (G x 256 @ 256 x 256).
__global__ __launch_bounds__(256, 2) void k5b_ctx(
    const float* __restrict__ agg, const ushort* __restrict__ Bp,
    const float* __restrict__ b_att, const float* __restrict__ bscale,
    float* __restrict__ ctx)
{
  __shared__ __align__(16) ushort A_lds[128 * 256];  // 64KB

  const int tid  = threadIdx.x;
  const int row0 = blockIdx.x * 128;

  #pragma unroll
  for (int i = 0; i < 16; i++) {
    int v = tid + i * 256;
    int r = v >> 5;
    int s = v & 31;
    int grow = row0 + r;
    f32x4 x0 = {0.f, 0.f, 0.f, 0.f}, x1 = {0.f, 0.f, 0.f, 0.f};
    if (grow < G_SEG) {
      const f32x4* p = (const f32x4*)(agg + (size_t)grow * H_DIM) + s * 2;
      x0 = p[0]; x1 = p[1];
    }
    bf16x8 t;
    t[0] = (short)f2bf(x0[0]); t[1] = (short)f2bf(x0[1]);
    t[2] = (short)f2bf(x0[2]); t[3] = (short)f2bf(x0[3]);
    t[4] = (short)f2bf(x1[0]); t[5] = (short)f2bf(x1[1]);
    t[6] = (short)f2bf(x1[2]); t[7] = (short)f2bf(x1[3]);
    *(bf16x8*)&A_lds[r * 256 + ((s ^ (r & 7)) * 8)] = t;
  }
  __syncthreads();

  const int wv  = tid >> 6;
  const int l   = tid & 63;
  const int l15 = l & 15, lq = l >> 4, l7 = l & 7;
  const int colbase = wv * 64 + l15;

  f32x4 acc[8][4];
  #pragma unroll
  for (int mf = 0; mf < 8; mf++)
    #pragma unroll
    for (int nf = 0; nf < 4; nf++)
      acc[mf][nf] = (f32x4){0.f, 0.f, 0.f, 0.f};

  for (int ks = 0; ks < 8; ks++) {
    int c = ks * 4 + lq;
    bf16x8 b[4];
    #pragma unroll
    for (int nf = 0; nf < 4; nf++)
      b[nf] = *(const bf16x8*)&Bp[(((c << 8) + colbase + nf * 16)) * 8];
    bf16x8 a[8];
    #pragma unroll
    for (int mf = 0; mf < 8; mf++)
      a[mf] = *(const bf16x8*)&A_lds[(mf * 16 + l15) * 256 + ((c ^ l7) * 8)];
    #pragma unroll
    for (int mf = 0; mf < 8; mf++)
      #pragma unroll
      for (int nf = 0; nf < 4; nf++)
        acc[mf][nf] = __builtin_amdgcn_mfma_f32_16x16x32_bf16(
            a[mf], b[nf], acc[mf][nf], 0, 0, 0);
  }

  float bias[4];
  #pragma unroll
  for (int nf = 0; nf < 4; nf++) bias[nf] = b_att[colbase + nf * 16];

  #pragma unroll
  for (int mf = 0; mf < 8; mf++) {
    #pragma unroll
    for (int r = 0; r < 4; r++) {
      int grow = row0 + mf * 16 + lq * 4 + r;
      if (grow < G_SEG) {
        float bsc = bscale[grow];
        #pragma unroll
        for (int nf = 0; nf < 4; nf++)
          ctx[(size_t)grow * H_DIM + colbase + nf * 16] =
              acc[mf][nf][r] + bias[nf] * bsc;
      }
    }
  }
}

// K6 (MFMA) v2: wave owns a 64-col slice for ALL 4 gates (acc[4][2][4],
// statically indexed) -> no gate_s LDS, single barrier, balanced waves.
__global__ __launch_bounds__(256, 2) void k6_mfma(
    const float* __restrict__ ctxbuf, const float* __restrict__ s_buf,
    const ushort* __restrict__ Bp6,
    const float* __restrict__ b_ih, const float* __restrict__ b_hh,
    float* __restrict__ out0)
{
  __shared__ __align__(16) ushort A_lds[32 * 512];   // 32KB

  const int tid  = threadIdx.x;
  const int row0 = blockIdx.x * 32;

  #pragma unroll
  for (int i = 0; i < 8; i++) {
    int v = tid + i * 256;
    int r = v >> 6;
    int s = v & 63;
    int g = row0 + r;
    f32x4 x0 = {0.f, 0.f, 0.f, 0.f}, x1 = {0.f, 0.f, 0.f, 0.f};
    if (g < G_SEG) {
      const f32x4* p = (s < 32)
          ? (const f32x4*)(ctxbuf + (size_t)g * H_DIM) + s * 2
          : (const f32x4*)(s_buf + (size_t)g * H_DIM) + (s - 32) * 2;
      x0 = p[0]; x1 = p[1];
      if (s < 32) {
        #pragma unroll
        for (int e = 0; e < 4; e++) {
          x0[e] = x0[e] > 0.f ? x0[e] : (__expf(x0[e]) - 1.f);
          x1[e] = x1[e] > 0.f ? x1[e] : (__expf(x1[e]) - 1.f);
        }
      }
    }
    bf16x8 t;
    t[0] = (short)f2bf(x0[0]); t[1] = (short)f2bf(x0[1]);
    t[2] = (short)f2bf(x0[2]); t[3] = (short)f2bf(x0[3]);
    t[4] = (short)f2bf(x1[0]); t[5] = (short)f2bf(x1[1]);
    t[6] = (short)f2bf(x1[2]); t[7] = (short)f2bf(x1[3]);
    *(bf16x8*)&A_lds[r * 512 + ((s ^ (r & 7)) * 8)] = t;
  }
  __syncthreads();

  const int wv  = tid >> 6;
  const int l   = tid & 63;
  const int l15 = l & 15, lq = l >> 4, l7 = l & 7;

  f32x4 acc[4][2][4];  // [gate][mf][nf]
  #pragma unroll
  for (int gt = 0; gt < 4; gt++)
    #pragma unroll
    for (int mf = 0; mf < 2; mf++)
      #pragma unroll
      for (int nf = 0; nf < 4; nf++)
        acc[gt][mf][nf] = (f32x4){0.f, 0.f, 0.f, 0.f};

  for (int ks = 0; ks < 16; ks++) {
    int c = ks * 4 + lq;  // k-chunk 0..63
    bf16x8 a[2];
    #pragma unroll
    for (int mf = 0; mf < 2; mf++)
      a[mf] = *(const bf16x8*)&A_lds[(mf * 16 + l15) * 512 + ((c ^ l7) * 8)];
    #pragma unroll
    for (int gt = 0; gt < 4; gt++) {
      if (gt == 2 && ks >= 8) continue;  // inn: K<256 only
      if (gt == 3 && ks < 8) continue;   // hn:  K>=256 only
      #pragma unroll
      for (int nf = 0; nf < 4; nf++) {
        int n = (gt << 8) + (wv << 6) + nf * 16 + l15;
        bf16x8 b = *(const bf16x8*)&Bp6[(((c << 10) + n)) * 8];
        acc[gt][0][nf] = __builtin_amdgcn_mfma_f32_16x16x32_bf16(
            a[0], b, acc[gt][0][nf], 0, 0, 0);
        acc[gt][1][nf] = __builtin_amdgcn_mfma_f32_16x16x32_bf16(
            a[1], b, acc[gt][1][nf], 0, 0, 0);
      }
    }
  }

  // epilogue fully in-register
  #pragma unroll
  for (int nf = 0; nf < 4; nf++) {
    int cc = (wv << 6) + nf * 16 + l15;
    float bir = b_ih[cc] + b_hh[cc];
    float biz = b_ih[256 + cc] + b_hh[256 + cc];
    float bin_ = b_ih[512 + cc];
    float bhn  = b_hh[512 + cc];
    #pragma unroll
    for (int mf = 0; mf < 2; mf++) {
      #pragma unroll
      for (int rr = 0; rr < 4; rr++) {
        int grow = row0 + mf * 16 + lq * 4 + rr;
        if (grow < G_SEG) {
          float v0 = acc[0][mf][nf][rr];
          float v1 = acc[1][mf][nf][rr];
          float v2 = acc[2][mf][nf][rr];
          float v3 = acc[3][mf][nf][rr];
          float r_ = 1.f / (1.f + __expf(-(v0 + bir)));
          float z_ = 1.f / (1.f + __expf(-(v1 + biz)));
          float n_ = tanhf(v2 + bin_ + r_ * (v3 + bhn));
          float sv = s_buf[(size_t)grow * H_DIM + cc];
          float nh = (1.f - z_) * n_ + z_ * sv;
          out0[(size_t)grow * H_DIM + cc] = nh > 0.f ? nh : 0.f;
        }
      }
    }
  }
}

extern "C" void kernel_launch(void* const* d_in, const int* in_sizes, int n_in,
                              void* d_out, int out_size, void* d_ws, size_t ws_size,
                              hipStream_t stream)
{
  (void)in_sizes; (void)n_in; (void)out_size; (void)ws_size;
  const float* node       = (const float*)d_in[0];
  const float* super_node = (const float*)d_in[1];
  const int*   seg        = (const int*)d_in[2];
  const float* w_align    = (const float*)d_in[3];
  const float* b_align    = (const float*)d_in[4];
  const float* w_att      = (const float*)d_in[5];
  const float* b_att      = (const float*)d_in[6];
  const float* w_ih       = (const float*)d_in[7];
  const float* w_hh       = (const float*)d_in[8];
  const float* b_ih       = (const float*)d_in[9];
  const float* b_hh       = (const float*)d_in[10];

  float* out0     = (float*)d_out;                               // G*H
  float* attn_out = (float*)d_out + (size_t)G_SEG * H_DIM;       // N

  float* ws     = (float*)d_ws;
  float* s_buf  = ws;                          //  6,400,000 f32
  float* sws    = ws + 6400000;                //     25,000
  float* agg    = ws + 6425000;                //  6,400,000
  ushort* Bp    = (ushort*)(ws + 12825000);    //  65,536 ushort (128KB)
  ushort* Bp6   = (ushort*)(ws + 12860000);    // 524,288 ushort (1MB)
  float* bscale = ws + 13125000;               //     25,000
  int*   starts = (int*)(ws + 13150000);       //     25,001 int
  float* ctx    = ws + 13200000;               //  6,400,000 (end 19.6M f32 = 78.4MB)

  k_starts<<<(N_NODES + 255) / 256, 256, 0, stream>>>(seg, starts);
  kPack<<<768, 256, 0, stream>>>(w_att, w_ih, w_hh, Bp, Bp6);
  k1_prep_super<<<G_SEG, 256, 0, stream>>>(super_node, w_align, s_buf, sws);
  kF_score_softmax_agg<<<G_SEG / SPB, 256, 0, stream>>>(
      node, starts, w_align, b_align, sws, attn_out, agg, bscale);
  k5b_ctx<<<(G_SEG + 127) / 128, 256, 0, stream>>>(agg, Bp, b_att, bscale, ctx);
  k6_mfma<<<(G_SEG + 31) / 32, 256, 0, stream>>>(ctx, s_buf, Bp6, b_ih, b_hh, out0);
}

// Round 11
// 263.404 us; speedup vs baseline: 1.2659x; 1.0265x over previous
//
#include <hip/hip_runtime.h>
#include <math.h>

#define N_NODES 500000
#define G_SEG   25000
#define H_DIM   256
#define SPB     4      // segments per kF block (one per wave)

typedef __attribute__((ext_vector_type(4))) float f32x4;
typedef __attribute__((ext_vector_type(8))) short bf16x8;

__device__ __forceinline__ float leaky(float x){ return x > 0.f ? x : 0.01f * x; }

// round-to-nearest-even f32 -> bf16
__device__ __forceinline__ ushort f2bf(float f){
  unsigned u = __float_as_uint(f);
  u += 0x7FFFu + ((u >> 16) & 1u);
  return (ushort)(u >> 16);
}

// KPrep: merged k1 + k_starts + kPack (saves 2 launches).
// block b (0..24999): k1 duty for segment b.
// blocks 0..1953: starts[] duty for rows b*256+t.
// blocks 2000..2255: pack w_attend -> Bp (kk = b-2000).
// blocks 2256..2767: pack GRU -> Bp6 (kk = b-2256).
__global__ __launch_bounds__(256) void kPrep(
    const float* __restrict__ sn, const float* __restrict__ w_align,
    const int* __restrict__ seg, const float* __restrict__ w_att,
    const float* __restrict__ w_ih, const float* __restrict__ w_hh,
    float* __restrict__ s_buf, float* __restrict__ sws,
    int* __restrict__ starts, ushort* __restrict__ Bp,
    ushort* __restrict__ Bp6)
{
  int b = blockIdx.x, t = threadIdx.x;

  // --- k1 duty: s = leaky(super_node); sws[b] = dot(s[b], w_align[H:2H])
  {
    float v = sn[b * H_DIM + t];
    float sv = leaky(v);
    s_buf[b * H_DIM + t] = sv;
    float p = sv * w_align[H_DIM + t];
    #pragma unroll
    for (int d = 1; d < 64; d <<= 1) p += __shfl_xor(p, d);
    __shared__ float red[4];
    int wid = t >> 6, lane = t & 63;
    if (lane == 0) red[wid] = p;
    __syncthreads();
    if (t == 0) sws[b] = red[0] + red[1] + red[2] + red[3];
  }

  // --- k_starts duty
  if (b < 1954) {
    int i = b * 256 + t;
    if (i < N_NODES) {
      int s = seg[i];
      int prev = (i == 0) ? -1 : seg[i - 1];
      for (int g = prev + 1; g <= s; g++) starts[g] = i;
      if (i == N_NODES - 1)
        for (int g = s + 1; g <= G_SEG; g++) starts[g] = N_NODES;
    }
  }
  // --- pack w_attend
  else if (b >= 2000 && b < 2256) {
    int kk = b - 2000;
    Bp[(((kk >> 3) << 8) + t) * 8 + (kk & 7)] = f2bf(w_att[kk * H_DIM + t]);
  }
  // --- pack GRU weights
  else if (b >= 2256 && b < 2768) {
    int kk = b - 2256;  // 0..511
    #pragma unroll
    for (int gate = 0; gate < 4; gate++) {
      float v;
      if (gate == 0)      v = (kk < 256) ? w_ih[kk * 768 + t]        : w_hh[(kk - 256) * 768 + t];
      else if (gate == 1) v = (kk < 256) ? w_ih[kk * 768 + 256 + t]  : w_hh[(kk - 256) * 768 + 256 + t];
      else if (gate == 2) v = (kk < 256) ? w_ih[kk * 768 + 512 + t]  : 0.f;
      else                v = (kk < 256) ? 0.f                       : w_hh[(kk - 256) * 768 + 512 + t];
      int n = (gate << 8) + t;
      Bp6[(((kk >> 3) << 10) + n) * 8 + (kk & 7)] = f2bf(v);
    }
  }
}

// KF v4: wave-per-segment with transpose-reduce.
// Per 4-row batch: 7 shfl reduce (vs 24), each lane owns row lane&3 ->
// 1 leaky + 1 exp per lane (vs 4), 2 shfl batch-max, 4 shfl p-broadcast.
__global__ __launch_bounds__(256) void kF_score_softmax_agg(
    const float* __restrict__ node, const int* __restrict__ starts,
    const float* __restrict__ w_align, const float* __restrict__ b_align,
    const float* __restrict__ sws,
    float* __restrict__ attn_out, float* __restrict__ agg,
    float* __restrict__ bscale)
{
  __shared__ int st_s[SPB + 1];
  const int tid = threadIdx.x;
  const int g0 = blockIdx.x * SPB;
  if (tid <= SPB) st_s[tid] = starts[g0 + tid];
  __syncthreads();

  const int wv = tid >> 6, lane = tid & 63;
  const float4 wvec = ((const float4*)w_align)[lane];
  const float b0 = b_align[0];

  const int g  = g0 + wv;
  const int st = st_s[wv], en = st_s[wv + 1];
  const float swsg = sws[g];

  float m = -3.4e38f, sum = 0.f;
  f32x4 pacc = {0.f, 0.f, 0.f, 0.f};

  int r = st;
  for (; r + 3 < en; r += 4) {
    f32x4 a0 = ((const f32x4*)node)[(size_t)(r    ) * 64 + lane];
    f32x4 a1 = ((const f32x4*)node)[(size_t)(r + 1) * 64 + lane];
    f32x4 a2 = ((const f32x4*)node)[(size_t)(r + 2) * 64 + lane];
    f32x4 a3 = ((const f32x4*)node)[(size_t)(r + 3) * 64 + lane];
    float d0 = a0[0]*wvec.x + a0[1]*wvec.y + a0[2]*wvec.z + a0[3]*wvec.w;
    float d1 = a1[0]*wvec.x + a1[1]*wvec.y + a1[2]*wvec.z + a1[3]*wvec.w;
    float d2 = a2[0]*wvec.x + a2[1]*wvec.y + a2[2]*wvec.z + a2[3]*wvec.w;
    float d3 = a3[0]*wvec.x + a3[1]*wvec.y + a3[2]*wvec.z + a3[3]*wvec.w;

    // transpose-reduce: after 3 shfl, lane owns row (lane&3)'s 4-group partial
    float k01 = (lane & 1) ? d1 : d0;
    float s01 = (lane & 1) ? d0 : d1;
    k01 += __shfl_xor(s01, 1);
    float k23 = (lane & 1) ? d3 : d2;
    float s23 = (lane & 1) ? d2 : d3;
    k23 += __shfl_xor(s23, 1);
    float x  = (lane & 2) ? k23 : k01;
    float xs = (lane & 2) ? k01 : k23;
    x += __shfl_xor(xs, 2);
    // butterfly over remaining 16 groups
    x += __shfl_xor(x, 4);
    x += __shfl_xor(x, 8);
    x += __shfl_xor(x, 16);
    x += __shfl_xor(x, 32);
    // x = full dot for row r + (lane&3), replicated across same (lane&3)

    float sc = leaky(x + swsg + b0);
    if (lane < 4) attn_out[r + lane] = sc;   // park raw score

    float bm = fmaxf(sc, __shfl_xor(sc, 1));
    bm = fmaxf(bm, __shfl_xor(bm, 2));       // wave-uniform batch max
    if (bm > m) {
      float scale = __expf(m - bm);          // first time: exp(-inf) = 0
      sum *= scale; pacc *= scale; m = bm;
    }
    float p = __expf(sc - m);                // this lane's row only
    float p0 = __shfl(p, 0);
    float p1 = __shfl(p, 1);
    float p2 = __shfl(p, 2);
    float p3 = __shfl(p, 3);
    sum += (p0 + p1) + (p2 + p3);
    pacc += p0 * a0 + p1 * a1;
    pacc += p2 * a2 + p3 * a3;
  }
  // tail rows: classic full butterfly
  for (; r < en; r++) {
    f32x4 a = ((const f32x4*)node)[(size_t)r * 64 + lane];
    float d = a[0]*wvec.x + a[1]*wvec.y + a[2]*wvec.z + a[3]*wvec.w;
    #pragma unroll
    for (int s2 = 1; s2 < 64; s2 <<= 1) d += __shfl_xor(d, s2);
    float sc = leaky(d + swsg + b0);
    if (lane == 0) attn_out[r] = sc;
    if (sc <= m) {
      float p = __expf(sc - m);
      sum += p;
      pacc += p * a;
    } else {
      float scale = __expf(m - sc);
      sum = sum * scale + 1.f;
      pacc = pacc * scale + a;
      m = sc;
    }
  }

  // wave-local finalize
  float invD = (sum > 0.f) ? 1.f / sum : 0.f;
  ((f32x4*)(agg + (size_t)g * H_DIM))[lane] = pacc * invD;
  if (lane == 0) bscale[g] = (sum > 0.f) ? 1.f : 0.f;
  for (int rr = st + lane; rr < en; rr += 64)
    attn_out[rr] = __expf(attn_out[rr] - m) * invD;
}

// K5b (MFMA): ctx = agg @ w_attend + bscale*b_attend  (G x 256 @ 256 x 256).
__global__ __launch_bounds__(256, 2) void k5b_ctx(
    const float* __restrict__ agg, const ushort* __restrict__ Bp,
    const float* __restrict__ b_att, const float* __restrict__ bscale,
    float* __restrict__ ctx)
{
  __shared__ __align__(16) ushort A_lds[128 * 256];  // 64KB

  const int tid  = threadIdx.x;
  const int row0 = blockIdx.x * 128;

  #pragma unroll
  for (int i = 0; i < 16; i++) {
    int v = tid + i * 256;
    int r = v >> 5;
    int s = v & 31;
    int grow = row0 + r;
    f32x4 x0 = {0.f, 0.f, 0.f, 0.f}, x1 = {0.f, 0.f, 0.f, 0.f};
    if (grow < G_SEG) {
      const f32x4* p = (const f32x4*)(agg + (size_t)grow * H_DIM) + s * 2;
      x0 = p[0]; x1 = p[1];
    }
    bf16x8 t;
    t[0] = (short)f2bf(x0[0]); t[1] = (short)f2bf(x0[1]);
    t[2] = (short)f2bf(x0[2]); t[3] = (short)f2bf(x0[3]);
    t[4] = (short)f2bf(x1[0]); t[5] = (short)f2bf(x1[1]);
    t[6] = (short)f2bf(x1[2]); t[7] = (short)f2bf(x1[3]);
    *(bf16x8*)&A_lds[r * 256 + ((s ^ (r & 7)) * 8)] = t;
  }
  __syncthreads();

  const int wv  = tid >> 6;
  const int l   = tid & 63;
  const int l15 = l & 15, lq = l >> 4, l7 = l & 7;
  const int colbase = wv * 64 + l15;

  f32x4 acc[8][4];
  #pragma unroll
  for (int mf = 0; mf < 8; mf++)
    #pragma unroll
    for (int nf = 0; nf < 4; nf++)
      acc[mf][nf] = (f32x4){0.f, 0.f, 0.f, 0.f};

  for (int ks = 0; ks < 8; ks++) {
    int c = ks * 4 + lq;
    bf16x8 b[4];
    #pragma unroll
    for (int nf = 0; nf < 4; nf++)
      b[nf] = *(const bf16x8*)&Bp[(((c << 8) + colbase + nf * 16)) * 8];
    bf16x8 a[8];
    #pragma unroll
    for (int mf = 0; mf < 8; mf++)
      a[mf] = *(const bf16x8*)&A_lds[(mf * 16 + l15) * 256 + ((c ^ l7) * 8)];
    #pragma unroll
    for (int mf = 0; mf < 8; mf++)
      #pragma unroll
      for (int nf = 0; nf < 4; nf++)
        acc[mf][nf] = __builtin_amdgcn_mfma_f32_16x16x32_bf16(
            a[mf], b[nf], acc[mf][nf], 0, 0, 0);
  }

  float bias[4];
  #pragma unroll
  for (int nf = 0; nf < 4; nf++) bias[nf] = b_att[colbase + nf * 16];

  #pragma unroll
  for (int mf = 0; mf < 8; mf++) {
    #pragma unroll
    for (int r = 0; r < 4; r++) {
      int grow = row0 + mf * 16 + lq * 4 + r;
      if (grow < G_SEG) {
        float bsc = bscale[grow];
        #pragma unroll
        for (int nf = 0; nf < 4; nf++)
          ctx[(size_t)grow * H_DIM + colbase + nf * 16] =
              acc[mf][nf][r] + bias[nf] * bsc;
      }
    }
  }
}

// K6 (MFMA) v3: 64 rows per block, 512 thr = 8 waves (halves per-block
// Bp6 L2 traffic vs 32-row blocks). Wave w: row-half (w>=4), col slice (w&3).
__global__ __launch_bounds__(512, 2) void k6_mfma(
    const float* __restrict__ ctxbuf, const float* __restrict__ s_buf,
    const ushort* __restrict__ Bp6,
    const float* __restrict__ b_ih, const float* __restrict__ b_hh,
    float* __restrict__ out0)
{
  __shared__ __align__(16) ushort A_lds[64 * 512];   // 64KB

  const int tid  = threadIdx.x;
  const int row0 = blockIdx.x * 64;

  #pragma unroll
  for (int i = 0; i < 8; i++) {
    int v = tid + i * 512;
    int r = v >> 6;          // 0..63
    int s = v & 63;
    int g = row0 + r;
    f32x4 x0 = {0.f, 0.f, 0.f, 0.f}, x1 = {0.f, 0.f, 0.f, 0.f};
    if (g < G_SEG) {
      const f32x4* p = (s < 32)
          ? (const f32x4*)(ctxbuf + (size_t)g * H_DIM) + s * 2
          : (const f32x4*)(s_buf + (size_t)g * H_DIM) + (s - 32) * 2;
      x0 = p[0]; x1 = p[1];
      if (s < 32) {
        #pragma unroll
        for (int e = 0; e < 4; e++) {
          x0[e] = x0[e] > 0.f ? x0[e] : (__expf(x0[e]) - 1.f);
          x1[e] = x1[e] > 0.f ? x1[e] : (__expf(x1[e]) - 1.f);
        }
      }
    }
    bf16x8 t;
    t[0] = (short)f2bf(x0[0]); t[1] = (short)f2bf(x0[1]);
    t[2] = (short)f2bf(x0[2]); t[3] = (short)f2bf(x0[3]);
    t[4] = (short)f2bf(x1[0]); t[5] = (short)f2bf(x1[1]);
    t[6] = (short)f2bf(x1[2]); t[7] = (short)f2bf(x1[3]);
    *(bf16x8*)&A_lds[r * 512 + ((s ^ (r & 7)) * 8)] = t;
  }
  __syncthreads();

  const int wv  = tid >> 6;          // 0..7
  const int rh  = (wv >> 2) * 32;    // row half base: 0 or 32
  const int cw  = (wv & 3) << 6;     // col slice base
  const int l   = tid & 63;
  const int l15 = l & 15, lq = l >> 4, l7 = l & 7;

  f32x4 acc[4][2][4];  // [gate][mf][nf]
  #pragma unroll
  for (int gt = 0; gt < 4; gt++)
    #pragma unroll
    for (int mf = 0; mf < 2; mf++)
      #pragma unroll
      for (int nf = 0; nf < 4; nf++)
        acc[gt][mf][nf] = (f32x4){0.f, 0.f, 0.f, 0.f};

  for (int ks = 0; ks < 16; ks++) {
    int c = ks * 4 + lq;  // k-chunk 0..63
    bf16x8 a[2];
    #pragma unroll
    for (int mf = 0; mf < 2; mf++)
      a[mf] = *(const bf16x8*)&A_lds[(rh + mf * 16 + l15) * 512 + ((c ^ l7) * 8)];
    #pragma unroll
    for (int gt = 0; gt < 4; gt++) {
      if (gt == 2 && ks >= 8) continue;  // inn: K<256 only
      if (gt == 3 && ks < 8) continue;   // hn:  K>=256 only
      #pragma unroll
      for (int nf = 0; nf < 4; nf++) {
        int n = (gt << 8) + cw + nf * 16 + l15;
        bf16x8 b = *(const bf16x8*)&Bp6[(((c << 10) + n)) * 8];
        acc[gt][0][nf] = __builtin_amdgcn_mfma_f32_16x16x32_bf16(
            a[0], b, acc[gt][0][nf], 0, 0, 0);
        acc[gt][1][nf] = __builtin_amdgcn_mfma_f32_16x16x32_bf16(
            a[1], b, acc[gt][1][nf], 0, 0, 0);
      }
    }
  }

  // epilogue fully in-register
  #pragma unroll
  for (int nf = 0; nf < 4; nf++) {
    int cc = cw + nf * 16 + l15;
    float bir = b_ih[cc] + b_hh[cc];
    float biz = b_ih[256 + cc] + b_hh[256 + cc];
    float bin_ = b_ih[512 + cc];
    float bhn  = b_hh[512 + cc];
    #pragma unroll
    for (int mf = 0; mf < 2; mf++) {
      #pragma unroll
      for (int rr = 0; rr < 4; rr++) {
        int grow = row0 + rh + mf * 16 + lq * 4 + rr;
        if (grow < G_SEG) {
          float v0 = acc[0][mf][nf][rr];
          float v1 = acc[1][mf][nf][rr];
          float v2 = acc[2][mf][nf][rr];
          float v3 = acc[3][mf][nf][rr];
          float r_ = 1.f / (1.f + __expf(-(v0 + bir)));
          float z_ = 1.f / (1.f + __expf(-(v1 + biz)));
          float n_ = tanhf(v2 + bin_ + r_ * (v3 + bhn));
          float sv = s_buf[(size_t)grow * H_DIM + cc];
          float nh = (1.f - z_) * n_ + z_ * sv;
          out0[(size_t)grow * H_DIM + cc] = nh > 0.f ? nh : 0.f;
        }
      }
    }
  }
}

extern "C" void kernel_launch(void* const* d_in, const int* in_sizes, int n_in,
                              void* d_out, int out_size, void* d_ws, size_t ws_size,
                              hipStream_t stream)
{
  (void)in_sizes; (void)n_in; (void)out_size; (void)ws_size;
  const float* node       = (const float*)d_in[0];
  const float* super_node = (const float*)d_in[1];
  const int*   seg        = (const int*)d_in[2];
  const float* w_align    = (const float*)d_in[3];
  const float* b_align    = (const float*)d_in[4];
  const float* w_att      = (const float*)d_in[5];
  const float* b_att      = (const float*)d_in[6];
  const float* w_ih       = (const float*)d_in[7];
  const float* w_hh       = (const float*)d_in[8];
  const float* b_ih       = (const float*)d_in[9];
  const float* b_hh       = (const float*)d_in[10];

  float* out0     = (float*)d_out;                               // G*H
  float* attn_out = (float*)d_out + (size_t)G_SEG * H_DIM;       // N

  float* ws     = (float*)d_ws;
  float* s_buf  = ws;                          //  6,400,000 f32
  float* sws    = ws + 6400000;                //     25,000
  float* agg    = ws + 6425000;                //  6,400,000
  ushort* Bp    = (ushort*)(ws + 12825000);    //  65,536 ushort (128KB)
  ushort* Bp6   = (ushort*)(ws + 12860000);    // 524,288 ushort (1MB)
  float* bscale = ws + 13125000;               //     25,000
  int*   starts = (int*)(ws + 13150000);       //     25,001 int
  float* ctx    = ws + 13200000;               //  6,400,000 (end 19.6M f32 = 78.4MB)

  kPrep<<<G_SEG, 256, 0, stream>>>(super_node, w_align, seg, w_att, w_ih, w_hh,
                                   s_buf, sws, starts, Bp, Bp6);
  kF_score_softmax_agg<<<G_SEG / SPB, 256, 0, stream>>>(
      node, starts, w_align, b_align, sws, attn_out, agg, bscale);
  k5b_ctx<<<(G_SEG + 127) / 128, 256, 0, stream>>>(agg, Bp, b_att, bscale, ctx);
  k6_mfma<<<(G_SEG + 63) / 64, 512, 0, stream>>>(ctx, s_buf, Bp6, b_ih, b_hh, out0);
}

// Round 12
// 256.531 us; speedup vs baseline: 1.2998x; 1.0268x over previous
//
#include <hip/hip_runtime.h>
#include <math.h>

#define N_NODES 500000
#define G_SEG   25000
#define H_DIM   256
#define SPB     4      // segments per kF block (one per wave)

typedef __attribute__((ext_vector_type(4))) float f32x4;
typedef __attribute__((ext_vector_type(8))) short bf16x8;

__device__ __forceinline__ float leaky(float x){ return x > 0.f ? x : 0.01f * x; }

// round-to-nearest-even f32 -> bf16
__device__ __forceinline__ ushort f2bf(float f){
  unsigned u = __float_as_uint(f);
  u += 0x7FFFu + ((u >> 16) & 1u);
  return (ushort)(u >> 16);
}

// KPrep v2: block = 4 waves; wave w owns segment g = b*4+w for the k1 duty
// (wave-local reduce, no LDS/barriers). Side duties by block id:
// blocks 0..1953: starts[]; blocks 2000..2255: pack Bp; 2256..2767: pack Bp6.
__global__ __launch_bounds__(256) void kPrep(
    const float* __restrict__ sn, const float* __restrict__ w_align,
    const int* __restrict__ seg, const float* __restrict__ w_att,
    const float* __restrict__ w_ih, const float* __restrict__ w_hh,
    float* __restrict__ s_buf, float* __restrict__ sws,
    int* __restrict__ starts, ushort* __restrict__ Bp,
    ushort* __restrict__ Bp6)
{
  int b = blockIdx.x, t = threadIdx.x;
  int wv = t >> 6, lane = t & 63;

  // --- k1 duty: wave per segment
  {
    int g = b * 4 + wv;
    f32x4 sv = ((const f32x4*)(sn + (size_t)g * H_DIM))[lane];
    f32x4 wa = ((const f32x4*)(w_align + H_DIM))[lane];
    #pragma unroll
    for (int e = 0; e < 4; e++) sv[e] = leaky(sv[e]);
    ((f32x4*)(s_buf + (size_t)g * H_DIM))[lane] = sv;
    float p = sv[0]*wa[0] + sv[1]*wa[1] + sv[2]*wa[2] + sv[3]*wa[3];
    #pragma unroll
    for (int d = 1; d < 64; d <<= 1) p += __shfl_xor(p, d);
    if (lane == 0) sws[g] = p;
  }

  // --- k_starts duty
  if (b < 1954) {
    int i = b * 256 + t;
    if (i < N_NODES) {
      int s = seg[i];
      int prev = (i == 0) ? -1 : seg[i - 1];
      for (int g = prev + 1; g <= s; g++) starts[g] = i;
      if (i == N_NODES - 1)
        for (int g = s + 1; g <= G_SEG; g++) starts[g] = N_NODES;
    }
  }
  // --- pack w_attend
  else if (b >= 2000 && b < 2256) {
    int kk = b - 2000;
    Bp[(((kk >> 3) << 8) + t) * 8 + (kk & 7)] = f2bf(w_att[kk * H_DIM + t]);
  }
  // --- pack GRU weights
  else if (b >= 2256 && b < 2768) {
    int kk = b - 2256;  // 0..511
    #pragma unroll
    for (int gate = 0; gate < 4; gate++) {
      float v;
      if (gate == 0)      v = (kk < 256) ? w_ih[kk * 768 + t]        : w_hh[(kk - 256) * 768 + t];
      else if (gate == 1) v = (kk < 256) ? w_ih[kk * 768 + 256 + t]  : w_hh[(kk - 256) * 768 + 256 + t];
      else if (gate == 2) v = (kk < 256) ? w_ih[kk * 768 + 512 + t]  : 0.f;
      else                v = (kk < 256) ? 0.f                       : w_hh[(kk - 256) * 768 + 512 + t];
      int n = (gate << 8) + t;
      Bp6[(((kk >> 3) << 10) + n) * 8 + (kk & 7)] = f2bf(v);
    }
  }
}

// KF v5: wave-per-segment, transpose-reduce, SOFTWARE-PIPELINED main loop:
// batch i+1's 4 loads issue before batch i's reduce/update chain, so HBM
// latency overlaps the shfl/exp work. Compute identical to v4.
__global__ __launch_bounds__(256) void kF_score_softmax_agg(
    const float* __restrict__ node, const int* __restrict__ starts,
    const float* __restrict__ w_align, const float* __restrict__ b_align,
    const float* __restrict__ sws,
    float* __restrict__ attn_out, float* __restrict__ agg,
    float* __restrict__ bscale)
{
  __shared__ int st_s[SPB + 1];
  const int tid = threadIdx.x;
  const int g0 = blockIdx.x * SPB;
  if (tid <= SPB) st_s[tid] = starts[g0 + tid];
  __syncthreads();

  const int wv = tid >> 6, lane = tid & 63;
  const float4 wvec = ((const float4*)w_align)[lane];
  const float b0 = b_align[0];

  const int g  = g0 + wv;
  const int st = st_s[wv], en = st_s[wv + 1];
  const float swsg = sws[g];

  float m = -3.4e38f, sum = 0.f;
  f32x4 pacc = {0.f, 0.f, 0.f, 0.f};

  int r = st;
  bool have = (r + 3 < en);
  f32x4 a0, a1, a2, a3;
  if (have) {
    a0 = ((const f32x4*)node)[(size_t)(r    ) * 64 + lane];
    a1 = ((const f32x4*)node)[(size_t)(r + 1) * 64 + lane];
    a2 = ((const f32x4*)node)[(size_t)(r + 2) * 64 + lane];
    a3 = ((const f32x4*)node)[(size_t)(r + 3) * 64 + lane];
  }
  while (have) {
    const int rn = r + 4;
    const bool haveN = (rn + 3 < en);
    f32x4 b0v, b1v, b2v, b3v;
    if (haveN) {   // prefetch next batch BEFORE the reduce chain
      b0v = ((const f32x4*)node)[(size_t)(rn    ) * 64 + lane];
      b1v = ((const f32x4*)node)[(size_t)(rn + 1) * 64 + lane];
      b2v = ((const f32x4*)node)[(size_t)(rn + 2) * 64 + lane];
      b3v = ((const f32x4*)node)[(size_t)(rn + 3) * 64 + lane];
    }

    float d0 = a0[0]*wvec.x + a0[1]*wvec.y + a0[2]*wvec.z + a0[3]*wvec.w;
    float d1 = a1[0]*wvec.x + a1[1]*wvec.y + a1[2]*wvec.z + a1[3]*wvec.w;
    float d2 = a2[0]*wvec.x + a2[1]*wvec.y + a2[2]*wvec.z + a2[3]*wvec.w;
    float d3 = a3[0]*wvec.x + a3[1]*wvec.y + a3[2]*wvec.z + a3[3]*wvec.w;

    // transpose-reduce: after 3 shfl, lane owns row (lane&3)'s partial
    float k01 = (lane & 1) ? d1 : d0;
    float s01 = (lane & 1) ? d0 : d1;
    k01 += __shfl_xor(s01, 1);
    float k23 = (lane & 1) ? d3 : d2;
    float s23 = (lane & 1) ? d2 : d3;
    k23 += __shfl_xor(s23, 1);
    float x  = (lane & 2) ? k23 : k01;
    float xs = (lane & 2) ? k01 : k23;
    x += __shfl_xor(xs, 2);
    x += __shfl_xor(x, 4);
    x += __shfl_xor(x, 8);
    x += __shfl_xor(x, 16);
    x += __shfl_xor(x, 32);

    float sc = leaky(x + swsg + b0);
    if (lane < 4) attn_out[r + lane] = sc;   // park raw score

    float bm = fmaxf(sc, __shfl_xor(sc, 1));
    bm = fmaxf(bm, __shfl_xor(bm, 2));       // wave-uniform batch max
    if (bm > m) {
      float scale = __expf(m - bm);          // first time: exp(-inf) = 0
      sum *= scale; pacc *= scale; m = bm;
    }
    float p = __expf(sc - m);                // this lane's row only
    float p0 = __shfl(p, 0);
    float p1 = __shfl(p, 1);
    float p2 = __shfl(p, 2);
    float p3 = __shfl(p, 3);
    sum += (p0 + p1) + (p2 + p3);
    pacc += p0 * a0 + p1 * a1;
    pacc += p2 * a2 + p3 * a3;

    a0 = b0v; a1 = b1v; a2 = b2v; a3 = b3v;
    r = rn; have = haveN;
  }
  // tail rows: classic full butterfly
  for (; r < en; r++) {
    f32x4 a = ((const f32x4*)node)[(size_t)r * 64 + lane];
    float d = a[0]*wvec.x + a[1]*wvec.y + a[2]*wvec.z + a[3]*wvec.w;
    #pragma unroll
    for (int s2 = 1; s2 < 64; s2 <<= 1) d += __shfl_xor(d, s2);
    float sc = leaky(d + swsg + b0);
    if (lane == 0) attn_out[r] = sc;
    if (sc <= m) {
      float p = __expf(sc - m);
      sum += p;
      pacc += p * a;
    } else {
      float scale = __expf(m - sc);
      sum = sum * scale + 1.f;
      pacc = pacc * scale + a;
      m = sc;
    }
  }

  // wave-local finalize
  float invD = (sum > 0.f) ? 1.f / sum : 0.f;
  ((f32x4*)(agg + (size_t)g * H_DIM))[lane] = pacc * invD;
  if (lane == 0) bscale[g] = (sum > 0.f) ? 1.f : 0.f;
  for (int rr = st + lane; rr < en; rr += 64)
    attn_out[rr] = __expf(attn_out[rr] - m) * invD;
}

// K5b (MFMA): ctx = agg @ w_attend + bscale*b_attend  (G x 256 @ 256 x 256).
__global__ __launch_bounds__(256, 2) void k5b_ctx(
    const float* __restrict__ agg, const ushort* __restrict__ Bp,
    const float* __restrict__ b_att, const float* __restrict__ bscale,
    float* __restrict__ ctx)
{
  __shared__ __align__(16) ushort A_lds[128 * 256];  // 64KB

  const int tid  = threadIdx.x;
  const int row0 = blockIdx.x * 128;

  #pragma unroll
  for (int i = 0; i < 16; i++) {
    int v = tid + i * 256;
    int r = v >> 5;
    int s = v & 31;
    int grow = row0 + r;
    f32x4 x0 = {0.f, 0.f, 0.f, 0.f}, x1 = {0.f, 0.f, 0.f, 0.f};
    if (grow < G_SEG) {
      const f32x4* p = (const f32x4*)(agg + (size_t)grow * H_DIM) + s * 2;
      x0 = p[0]; x1 = p[1];
    }
    bf16x8 t;
    t[0] = (short)f2bf(x0[0]); t[1] = (short)f2bf(x0[1]);
    t[2] = (short)f2bf(x0[2]); t[3] = (short)f2bf(x0[3]);
    t[4] = (short)f2bf(x1[0]); t[5] = (short)f2bf(x1[1]);
    t[6] = (short)f2bf(x1[2]); t[7] = (short)f2bf(x1[3]);
    *(bf16x8*)&A_lds[r * 256 + ((s ^ (r & 7)) * 8)] = t;
  }
  __syncthreads();

  const int wv  = tid >> 6;
  const int l   = tid & 63;
  const int l15 = l & 15, lq = l >> 4, l7 = l & 7;
  const int colbase = wv * 64 + l15;

  f32x4 acc[8][4];
  #pragma unroll
  for (int mf = 0; mf < 8; mf++)
    #pragma unroll
    for (int nf = 0; nf < 4; nf++)
      acc[mf][nf] = (f32x4){0.f, 0.f, 0.f, 0.f};

  for (int ks = 0; ks < 8; ks++) {
    int c = ks * 4 + lq;
    bf16x8 b[4];
    #pragma unroll
    for (int nf = 0; nf < 4; nf++)
      b[nf] = *(const bf16x8*)&Bp[(((c << 8) + colbase + nf * 16)) * 8];
    bf16x8 a[8];
    #pragma unroll
    for (int mf = 0; mf < 8; mf++)
      a[mf] = *(const bf16x8*)&A_lds[(mf * 16 + l15) * 256 + ((c ^ l7) * 8)];
    #pragma unroll
    for (int mf = 0; mf < 8; mf++)
      #pragma unroll
      for (int nf = 0; nf < 4; nf++)
        acc[mf][nf] = __builtin_amdgcn_mfma_f32_16x16x32_bf16(
            a[mf], b[nf], acc[mf][nf], 0, 0, 0);
  }

  float bias[4];
  #pragma unroll
  for (int nf = 0; nf < 4; nf++) bias[nf] = b_att[colbase + nf * 16];

  #pragma unroll
  for (int mf = 0; mf < 8; mf++) {
    #pragma unroll
    for (int r = 0; r < 4; r++) {
      int grow = row0 + mf * 16 + lq * 4 + r;
      if (grow < G_SEG) {
        float bsc = bscale[grow];
        #pragma unroll
        for (int nf = 0; nf < 4; nf++)
          ctx[(size_t)grow * H_DIM + colbase + nf * 16] =
              acc[mf][nf][r] + bias[nf] * bsc;
      }
    }
  }
}

// K6 (MFMA) v3: 64 rows per block, 512 thr = 8 waves. Wave w: row-half
// (w>=4), col slice (w&3).
__global__ __launch_bounds__(512, 2) void k6_mfma(
    const float* __restrict__ ctxbuf, const float* __restrict__ s_buf,
    const ushort* __restrict__ Bp6,
    const float* __restrict__ b_ih, const float* __restrict__ b_hh,
    float* __restrict__ out0)
{
  __shared__ __align__(16) ushort A_lds[64 * 512];   // 64KB

  const int tid  = threadIdx.x;
  const int row0 = blockIdx.x * 64;

  #pragma unroll
  for (int i = 0; i < 8; i++) {
    int v = tid + i * 512;
    int r = v >> 6;          // 0..63
    int s = v & 63;
    int g = row0 + r;
    f32x4 x0 = {0.f, 0.f, 0.f, 0.f}, x1 = {0.f, 0.f, 0.f, 0.f};
    if (g < G_SEG) {
      const f32x4* p = (s < 32)
          ? (const f32x4*)(ctxbuf + (size_t)g * H_DIM) + s * 2
          : (const f32x4*)(s_buf + (size_t)g * H_DIM) + (s - 32) * 2;
      x0 = p[0]; x1 = p[1];
      if (s < 32) {
        #pragma unroll
        for (int e = 0; e < 4; e++) {
          x0[e] = x0[e] > 0.f ? x0[e] : (__expf(x0[e]) - 1.f);
          x1[e] = x1[e] > 0.f ? x1[e] : (__expf(x1[e]) - 1.f);
        }
      }
    }
    bf16x8 t;
    t[0] = (short)f2bf(x0[0]); t[1] = (short)f2bf(x0[1]);
    t[2] = (short)f2bf(x0[2]); t[3] = (short)f2bf(x0[3]);
    t[4] = (short)f2bf(x1[0]); t[5] = (short)f2bf(x1[1]);
    t[6] = (short)f2bf(x1[2]); t[7] = (short)f2bf(x1[3]);
    *(bf16x8*)&A_lds[r * 512 + ((s ^ (r & 7)) * 8)] = t;
  }
  __syncthreads();

  const int wv  = tid >> 6;          // 0..7
  const int rh  = (wv >> 2) * 32;    // row half base: 0 or 32
  const int cw  = (wv & 3) << 6;     // col slice base
  const int l   = tid & 63;
  const int l15 = l & 15, lq = l >> 4, l7 = l & 7;

  f32x4 acc[4][2][4];  // [gate][mf][nf]
  #pragma unroll
  for (int gt = 0; gt < 4; gt++)
    #pragma unroll
    for (int mf = 0; mf < 2; mf++)
      #pragma unroll
      for (int nf = 0; nf < 4; nf++)
        acc[gt][mf][nf] = (f32x4){0.f, 0.f, 0.f, 0.f};

  for (int ks = 0; ks < 16; ks++) {
    int c = ks * 4 + lq;  // k-chunk 0..63
    bf16x8 a[2];
    #pragma unroll
    for (int mf = 0; mf < 2; mf++)
      a[mf] = *(const bf16x8*)&A_lds[(rh + mf * 16 + l15) * 512 + ((c ^ l7) * 8)];
    #pragma unroll
    for (int gt = 0; gt < 4; gt++) {
      if (gt == 2 && ks >= 8) continue;  // inn: K<256 only
      if (gt == 3 && ks < 8) continue;   // hn:  K>=256 only
      #pragma unroll
      for (int nf = 0; nf < 4; nf++) {
        int n = (gt << 8) + cw + nf * 16 + l15;
        bf16x8 b = *(const bf16x8*)&Bp6[(((c << 10) + n)) * 8];
        acc[gt][0][nf] = __builtin_amdgcn_mfma_f32_16x16x32_bf16(
            a[0], b, acc[gt][0][nf], 0, 0, 0);
        acc[gt][1][nf] = __builtin_amdgcn_mfma_f32_16x16x32_bf16(
            a[1], b, acc[gt][1][nf], 0, 0, 0);
      }
    }
  }

  // epilogue fully in-register
  #pragma unroll
  for (int nf = 0; nf < 4; nf++) {
    int cc = cw + nf * 16 + l15;
    float bir = b_ih[cc] + b_hh[cc];
    float biz = b_ih[256 + cc] + b_hh[256 + cc];
    float bin_ = b_ih[512 + cc];
    float bhn  = b_hh[512 + cc];
    #pragma unroll
    for (int mf = 0; mf < 2; mf++) {
      #pragma unroll
      for (int rr = 0; rr < 4; rr++) {
        int grow = row0 + rh + mf * 16 + lq * 4 + rr;
        if (grow < G_SEG) {
          float v0 = acc[0][mf][nf][rr];
          float v1 = acc[1][mf][nf][rr];
          float v2 = acc[2][mf][nf][rr];
          float v3 = acc[3][mf][nf][rr];
          float r_ = 1.f / (1.f + __expf(-(v0 + bir)));
          float z_ = 1.f / (1.f + __expf(-(v1 + biz)));
          float n_ = tanhf(v2 + bin_ + r_ * (v3 + bhn));
          float sv = s_buf[(size_t)grow * H_DIM + cc];
          float nh = (1.f - z_) * n_ + z_ * sv;
          out0[(size_t)grow * H_DIM + cc] = nh > 0.f ? nh : 0.f;
        }
      }
    }
  }
}

extern "C" void kernel_launch(void* const* d_in, const int* in_sizes, int n_in,
                              void* d_out, int out_size, void* d_ws, size_t ws_size,
                              hipStream_t stream)
{
  (void)in_sizes; (void)n_in; (void)out_size; (void)ws_size;
  const float* node       = (const float*)d_in[0];
  const float* super_node = (const float*)d_in[1];
  const int*   seg        = (const int*)d_in[2];
  const float* w_align    = (const float*)d_in[3];
  const float* b_align    = (const float*)d_in[4];
  const float* w_att      = (const float*)d_in[5];
  const float* b_att      = (const float*)d_in[6];
  const float* w_ih       = (const float*)d_in[7];
  const float* w_hh       = (const float*)d_in[8];
  const float* b_ih       = (const float*)d_in[9];
  const float* b_hh       = (const float*)d_in[10];

  float* out0     = (float*)d_out;                               // G*H
  float* attn_out = (float*)d_out + (size_t)G_SEG * H_DIM;       // N

  float* ws     = (float*)d_ws;
  float* s_buf  = ws;                          //  6,400,000 f32
  float* sws    = ws + 6400000;                //     25,000
  float* agg    = ws + 6425000;                //  6,400,000
  ushort* Bp    = (ushort*)(ws + 12825000);    //  65,536 ushort (128KB)
  ushort* Bp6   = (ushort*)(ws + 12860000);    // 524,288 ushort (1MB)
  float* bscale = ws + 13125000;               //     25,000
  int*   starts = (int*)(ws + 13150000);       //     25,001 int
  float* ctx    = ws + 13200000;               //  6,400,000 (end 19.6M f32 = 78.4MB)

  kPrep<<<G_SEG / 4, 256, 0, stream>>>(super_node, w_align, seg, w_att, w_ih, w_hh,
                                       s_buf, sws, starts, Bp, Bp6);
  kF_score_softmax_agg<<<G_SEG / SPB, 256, 0, stream>>>(
      node, starts, w_align, b_align, sws, attn_out, agg, bscale);
  k5b_ctx<<<(G_SEG + 127) / 128, 256, 0, stream>>>(agg, Bp, b_att, bscale, ctx);
  k6_mfma<<<(G_SEG + 63) / 64, 512, 0, stream>>>(ctx, s_buf, Bp6, b_ih, b_hh, out0);
}